// Round 2
// baseline (48508.832 us; speedup 1.0000x reference)
//
#include <hip/hip_runtime.h>
#include <hip/hip_cooperative_groups.h>
#include <stdint.h>

namespace cg = cooperative_groups;

#define BATCH 128
#define TSTEPS 250
#define NIN 700
#define NHID 1024
#define NBR 4
#define NOUT 20
#define KDIM 1724          // NIN + NHID
#define NR 4096            // NHID * NBR
#define VTH 0.5f

// ---------------- setup kernels ----------------

__global__ void setup_small(const float* __restrict__ tau_m1, const float* __restrict__ tau_n,
                            const float* __restrict__ tau_m2, const float* __restrict__ W2,
                            float* __restrict__ alpha1, float* __restrict__ beta,
                            float* __restrict__ alpha2, float* __restrict__ W2T) {
    int i = blockIdx.x * blockDim.x + threadIdx.x;
    if (i < NHID)  alpha1[i] = 1.f / (1.f + expf(-tau_m1[i]));
    if (i < NR)    beta[i]   = 1.f / (1.f + expf(-tau_n[i]));   // tau_n row-major [HID][BR] == flat r
    if (i < 32)    alpha2[i] = (i < NOUT) ? 1.f / (1.f + expf(-tau_m2[i])) : 0.f;
    if (i < NHID * 32) {                                        // W2T padded [1024][32]
        int j = i >> 5, o = i & 31;
        W2T[i] = (o < NOUT) ? W2[o * NHID + j] : 0.f;
    }
}

// W1xT[k][r] (k<700) and W1hTb[blk][n][16] masked transposes
__global__ void setup_weights(const float* __restrict__ W1, const int* __restrict__ mask,
                              float* __restrict__ W1xT, float* __restrict__ W1hTb) {
    const int total1 = NIN * NR;            // 2,867,200
    const int total2 = 256 * 16384;         // 4,194,304
    for (int i = blockIdx.x * blockDim.x + threadIdx.x; i < total1 + total2;
         i += gridDim.x * blockDim.x) {
        if (i < total1) {
            int k = i >> 12, r = i & 4095;
            size_t src = (size_t)r * KDIM + k;
            W1xT[i] = W1[src] * (float)mask[src];
        } else {
            int j = i - total1;
            int blk = j >> 14, rem = j & 16383;
            int n = rem >> 4, rl = rem & 15;
            int r = (blk << 4) + rl;
            size_t src = (size_t)r * KDIM + NIN + n;
            W1hTb[j] = W1[src] * (float)mask[src];
        }
    }
}

__global__ void init_state(const float* __restrict__ mem1_0, const float* __restrict__ mem2_0,
                           float* __restrict__ mem1, float* __restrict__ mem2,
                           float* __restrict__ spk2, float* __restrict__ d_inp,
                           uint32_t* __restrict__ spkg) {
    int i = blockIdx.x * blockDim.x + threadIdx.x;
    if (i < BATCH * NR) d_inp[i] = 0.f;
    if (i < BATCH * NHID) mem1[i] = mem1_0[i];
    if (i < BATCH * NOUT) { mem2[i] = mem2_0[i]; spk2[i] = 0.f; }
    if (i < 2 * BATCH * 64) spkg[i] = 0u;   // both spike-mask buffers
}

// ---------------- FFX GEMM: ffx[dt][b][r] = sum_k x[b][t0+dt][k]*W1xT[k][r] + b1[r] ----------------

#define GBM 128
#define GBN 128
#define GBK 16

__global__ __launch_bounds__(256) void ffx_gemm(const float* __restrict__ x,
                                                const float* __restrict__ W1xT,
                                                const float* __restrict__ b1,
                                                float* __restrict__ ffx, int t0) {
    __shared__ float As[GBK][GBM];
    __shared__ float Bs[GBK][GBN];
    int dt = blockIdx.x, bn = blockIdx.y;
    int tid = threadIdx.x;
    int tn = tid & 15, tm = tid >> 4;

    float acc[8][8];
#pragma unroll
    for (int i = 0; i < 8; ++i)
#pragma unroll
        for (int j = 0; j < 8; ++j) acc[i][j] = 0.f;

    // A-load mapping: 2 threads per row; row within tile == batch index
    int m_l = tid >> 1;
    const float* xrow = x + ((size_t)m_l * TSTEPS + t0 + dt) * NIN;
    int kh = (tid & 1) * 8;
    // B-load mapping
    int kb = tid >> 4;
    int nb = (tid & 15) * 8;

    for (int k0 = 0; k0 < NIN; k0 += GBK) {
        float av[8];
#pragma unroll
        for (int u = 0; u < 8; ++u) {
            int k = k0 + kh + u;
            av[u] = (k < NIN) ? xrow[k] : 0.f;
        }
#pragma unroll
        for (int u = 0; u < 8; ++u) As[kh + u][m_l] = av[u];

        bool kok = (k0 + kb) < NIN;
        const float* bp = W1xT + (size_t)(k0 + kb) * NR + bn * GBN + nb;
        float bv[8];
#pragma unroll
        for (int u = 0; u < 8; ++u) bv[u] = kok ? bp[u] : 0.f;
#pragma unroll
        for (int u = 0; u < 8; ++u) Bs[kb][nb + u] = bv[u];

        __syncthreads();
#pragma unroll
        for (int kk = 0; kk < GBK; ++kk) {
            float a[8], b[8];
#pragma unroll
            for (int u = 0; u < 8; ++u) a[u] = As[kk][tm * 8 + u];
#pragma unroll
            for (int u = 0; u < 8; ++u) b[u] = Bs[kk][tn * 8 + u];
#pragma unroll
            for (int i = 0; i < 8; ++i)
#pragma unroll
                for (int j = 0; j < 8; ++j) acc[i][j] += a[i] * b[j];
        }
        __syncthreads();
    }

    float bias[8];
#pragma unroll
    for (int j = 0; j < 8; ++j) bias[j] = b1[bn * GBN + tn * 8 + j];
#pragma unroll
    for (int i = 0; i < 8; ++i) {
        int brow = tm * 8 + i;
        float* cp = ffx + ((size_t)dt * BATCH + brow) * NR + bn * GBN + tn * 8;
#pragma unroll
        for (int j = 0; j < 8; ++j) cp[j] = acc[i][j] + bias[j];
    }
}

// ---------------- persistent cooperative time-loop kernel ----------------
// grid 256 blocks x 1024 threads (16 waves/CU, 1 block/CU, 102 KB LDS).
// Block blk owns r-tile [blk*16, blk*16+16) = neurons [blk*4, blk*4+4).
// Thread (bg=tid>>4, r_l=tid&15) owns batches {2bg, 2bg+1} for r-value r_l.
// d_inp/mem1 live in registers across the whole chunk; weights live in LDS.
// Blocks 0..3 also run layer-2 + log_softmax for step t-1 (32 batches each).
// Spike masks double-buffered in global; byte g of batch b = spikes of neurons 4g..4g+3.

__global__ __launch_bounds__(1024, 4) void persist_kernel(
    const float* __restrict__ alpha1, const float* __restrict__ beta,
    const float* __restrict__ alpha2, float* __restrict__ mem1, float* __restrict__ mem2,
    float* __restrict__ spk2, float* __restrict__ d_inp,
    const float* __restrict__ W1hTb, const float* __restrict__ W2T,
    const float* __restrict__ ffx, const float* __restrict__ b2v,
    float* __restrict__ out, uint32_t* __restrict__ spkg,
    int t0, int tc, int last) {
    __shared__ float lds_W[NHID * 17];      // padded: conflict-free column reads
    __shared__ uint32_t lds_mask[BATCH * 64];
    cg::grid_group grid = cg::this_grid();

    const int blk = blockIdx.x;
    const int tid = threadIdx.x;

    // stage recurrent weight slice once for the whole chunk
    {
        const float4* wsrc = (const float4*)(W1hTb + (size_t)blk * 16384);
        for (int i4 = tid; i4 < 4096; i4 += 1024) {
            float4 v = wsrc[i4];
            int n = i4 >> 2, rb = (i4 & 3) * 4;
            lds_W[n * 17 + rb + 0] = v.x;
            lds_W[n * 17 + rb + 1] = v.y;
            lds_W[n * 17 + rb + 2] = v.z;
            lds_W[n * 17 + rb + 3] = v.w;
        }
    }

    const int r_l = tid & 15;
    const int bg  = tid >> 4;               // 0..63
    const int r_g = (blk << 4) + r_l;
    const int neuron = (blk << 2) + (r_l >> 2);
    const float beta_r = beta[r_g];
    const float al = alpha1[neuron];
    const int wv = blk >> 2;
    const int bitbase = ((blk & 3) << 3) + (r_l >> 2);

    // register-resident layer-1 state
    float di[2], mem[2];
#pragma unroll
    for (int i = 0; i < 2; ++i) {
        int b = bg * 2 + i;
        di[i]  = d_inp[(size_t)b * NR + r_g];
        mem[i] = mem1[(size_t)b * NHID + neuron];
    }

    // register-resident layer-2 state (blocks 0..3: 32 batches x 32 lanes)
    float m2 = 0.f, s2 = 0.f, a2 = 0.f, bo = 0.f;
    int b2i = 0, o2 = 0;
    if (blk < 4) {
        b2i = (blk << 5) + (tid >> 5);
        o2 = tid & 31;
        if (o2 < NOUT) {
            a2 = alpha2[o2];
            bo = b2v[o2];
            m2 = mem2[b2i * NOUT + o2];
            s2 = spk2[b2i * NOUT + o2];
        }
    }

    const int t_end = t0 + tc + (last ? 1 : 0);
    for (int tt = t0; tt < t_end; ++tt) {
        const uint32_t* mprev = spkg + (size_t)((tt + 1) & 1) * (BATCH * 64);
        __syncthreads();                    // previous iteration done with lds_mask
        for (int i = tid; i < BATCH * 64; i += 1024) lds_mask[i] = mprev[i];
        __syncthreads();

        // ---------- phase 1: recurrent accumulate + dendrite + mem1 + spike ----------
        if (tt < TSTEPS) {
            const float* ffrow = ffx + (size_t)(tt - t0) * (BATCH * NR);
            uint8_t* nxt = (uint8_t*)(spkg + (size_t)(tt & 1) * (BATCH * 64));
#pragma unroll
            for (int i = 0; i < 2; ++i) {
                int b = bg * 2 + i;
                const uint32_t* mw = &lds_mask[b * 64];
                float a = 0.f;
                for (int w = 0; w < 64; ++w) {
                    uint32_t bits = mw[w];
                    while (bits) {
                        int p = __builtin_ctz(bits);
                        bits &= bits - 1;
                        int n = (w << 4) + ((p >> 3) << 2) + (p & 7);
                        a += lds_W[n * 17 + r_l];
                    }
                }
                float ff = a + ffrow[(size_t)b * NR + r_g];
                di[i] = beta_r * di[i] + (1.f - beta_r) * ff;
                float ls = di[i] + __shfl_xor(di[i], 1);
                ls += __shfl_xor(ls, 2);
                float sp_prev = (float)((mw[wv] >> bitbase) & 1u);
                float mn = mem[i] * al + (1.f - al) * ls - VTH * sp_prev;
                mem[i] = mn;
                bool spk = (mn - VTH) > 0.f;
                unsigned long long bal = __ballot(spk && ((r_l & 3) == 0));
                if (r_l == 0) {
                    int base = (bg & 3) << 4;
                    uint32_t nib = (uint32_t)((bal >> base) & 1ull) |
                                   ((uint32_t)((bal >> (base + 4)) & 1ull) << 1) |
                                   ((uint32_t)((bal >> (base + 8)) & 1ull) << 2) |
                                   ((uint32_t)((bal >> (base + 12)) & 1ull) << 3);
                    nxt[b * 256 + blk] = (uint8_t)nib;
                }
            }
        }

        // ---------- phase 2 (for step tt-1): layer 2 + log_softmax ----------
        if (tt > 0 && blk < 4) {
            const uint32_t* mw = &lds_mask[b2i * 64];
            float d2 = bo;
            for (int w = 0; w < 64; ++w) {
                uint32_t bits = mw[w];
                while (bits) {
                    int p = __builtin_ctz(bits);
                    bits &= bits - 1;
                    int n = (w << 4) + ((p >> 3) << 2) + (p & 7);
                    d2 += W2T[(n << 5) + o2];
                }
            }
            float m2n = m2 * a2 + (1.f - a2) * d2 - VTH * s2;
            m2 = m2n;
            s2 = ((m2n - VTH) > 0.f) ? 1.f : 0.f;
            float v = (o2 < NOUT) ? m2n : -3.4e38f;
#pragma unroll
            for (int off = 16; off >= 1; off >>= 1) v = fmaxf(v, __shfl_xor(v, off, 32));
            float e = (o2 < NOUT) ? expf(m2n - v) : 0.f;
            float s = e;
#pragma unroll
            for (int off = 16; off >= 1; off >>= 1) s += __shfl_xor(s, off, 32);
            if (o2 < NOUT) out[((size_t)b2i * NOUT + o2) * TSTEPS + (tt - 1)] = (m2n - v) - logf(s);
        }

        if (tt + 1 < t_end) {
            __threadfence();                // release spike-mask writes (cross-XCD)
            grid.sync();
            __threadfence();                // acquire: invalidate stale cached masks
        }
    }

    // save state for next chunk
#pragma unroll
    for (int i = 0; i < 2; ++i) {
        int b = bg * 2 + i;
        d_inp[(size_t)b * NR + r_g] = di[i];
        if ((r_l & 3) == 0) mem1[(size_t)b * NHID + neuron] = mem[i];
    }
    if (blk < 4 && o2 < NOUT) {
        mem2[b2i * NOUT + o2] = m2;
        spk2[b2i * NOUT + o2] = s2;
    }
}

// ---------------- fallback per-step kernel (if cooperative launch refused) ----------------

__global__ __launch_bounds__(512) void step_kernel(
    const float* __restrict__ alpha1, const float* __restrict__ beta,
    const float* __restrict__ alpha2, float* __restrict__ mem1, float* __restrict__ mem2,
    float* __restrict__ spk2, float* __restrict__ d_inp,
    const float* __restrict__ W1hTb, const float* __restrict__ W2T,
    const float* __restrict__ ffx, const float* __restrict__ b2,
    float* __restrict__ out, const uint32_t* __restrict__ spkg_prev,
    uint32_t* __restrict__ spkg_next, int t, int t_local) {
    __shared__ float lds_W[NHID * 17];
    __shared__ uint32_t lds_mask[BATCH * 64];

    int blk = blockIdx.x;
    int tid = threadIdx.x;

    if (t < TSTEPS) {
        const float4* wsrc = (const float4*)(W1hTb + (size_t)blk * 16384);
        for (int i4 = tid; i4 < 4096; i4 += 512) {
            float4 v = wsrc[i4];
            int n = i4 >> 2, rb = (i4 & 3) * 4;
            lds_W[n * 17 + rb + 0] = v.x;
            lds_W[n * 17 + rb + 1] = v.y;
            lds_W[n * 17 + rb + 2] = v.z;
            lds_W[n * 17 + rb + 3] = v.w;
        }
    }
    for (int i = tid; i < BATCH * 64; i += 512) lds_mask[i] = spkg_prev[i];
    __syncthreads();

    if (t < TSTEPS) {
        int r_l = tid & 15;
        int bg = tid >> 4;
        float acc[4];
#pragma unroll
        for (int i = 0; i < 4; ++i) {
            int b = bg * 4 + i;
            const uint32_t* mw = &lds_mask[b * 64];
            float a = 0.f;
            for (int w = 0; w < 64; ++w) {
                uint32_t bits = mw[w];
                while (bits) {
                    int p = __builtin_ctz(bits);
                    bits &= bits - 1;
                    int n = (w << 4) + ((p >> 3) << 2) + (p & 7);
                    a += lds_W[n * 17 + r_l];
                }
            }
            acc[i] = a;
        }

        int r_g = (blk << 4) + r_l;
        float beta_r = beta[r_g];
        int neuron = (blk << 2) + (r_l >> 2);
        float al = alpha1[neuron];
        int wv = blk >> 2;
        int bitbase = ((blk & 3) << 3) + (r_l >> 2);

#pragma unroll
        for (int i = 0; i < 4; ++i) {
            int b = bg * 4 + i;
            float ff = acc[i] + ffx[((size_t)t_local * BATCH + b) * NR + r_g];
            size_t di_idx = (size_t)b * NR + r_g;
            float di = d_inp[di_idx];
            di = beta_r * di + (1.f - beta_r) * ff;
            d_inp[di_idx] = di;
            float ls = di + __shfl_xor(di, 1);
            ls += __shfl_xor(ls, 2);
            float m = mem1[b * NHID + neuron];
            float sp_prev = (float)((lds_mask[b * 64 + wv] >> bitbase) & 1u);
            float mn = m * al + (1.f - al) * ls - VTH * sp_prev;
            bool spk = (mn - VTH) > 0.f;
            if ((r_l & 3) == 0) mem1[b * NHID + neuron] = mn;
            unsigned long long bal = __ballot(spk && ((r_l & 3) == 0));
            if (r_l == 0) {
                int base = (bg & 3) << 4;
                uint32_t nib = (uint32_t)((bal >> base) & 1ull) |
                               ((uint32_t)((bal >> (base + 4)) & 1ull) << 1) |
                               ((uint32_t)((bal >> (base + 8)) & 1ull) << 2) |
                               ((uint32_t)((bal >> (base + 12)) & 1ull) << 3);
                ((uint8_t*)spkg_next)[b * 256 + blk] = (uint8_t)nib;
            }
        }
    }

    if (t > 0 && blk < 8) {
        int b = (blk << 4) + (tid >> 5);
        int o = tid & 31;
        const uint32_t* mw = &lds_mask[b * 64];
        float d2 = 0.f;
        for (int w = 0; w < 64; ++w) {
            uint32_t bits = mw[w];
            while (bits) {
                int p = __builtin_ctz(bits);
                bits &= bits - 1;
                int n = (w << 4) + ((p >> 3) << 2) + (p & 7);
                d2 += W2T[(n << 5) + o];
            }
        }
        float a2 = (o < NOUT) ? alpha2[o] : 0.f;
        d2 += (o < NOUT) ? b2[o] : 0.f;
        float m2 = (o < NOUT) ? mem2[b * NOUT + o] : 0.f;
        float s2 = (o < NOUT) ? spk2[b * NOUT + o] : 0.f;
        float m2n = m2 * a2 + (1.f - a2) * d2 - VTH * s2;
        if (o < NOUT) {
            mem2[b * NOUT + o] = m2n;
            spk2[b * NOUT + o] = ((m2n - VTH) > 0.f) ? 1.f : 0.f;
        }
        float v = (o < NOUT) ? m2n : -3.4e38f;
#pragma unroll
        for (int off = 16; off >= 1; off >>= 1) v = fmaxf(v, __shfl_xor(v, off, 32));
        float e = (o < NOUT) ? expf(m2n - v) : 0.f;
        float s = e;
#pragma unroll
        for (int off = 16; off >= 1; off >>= 1) s += __shfl_xor(s, off, 32);
        if (o < NOUT) out[((size_t)b * NOUT + o) * TSTEPS + (t - 1)] = (m2n - v) - logf(s);
    }
}

// ---------------- host ----------------

extern "C" void kernel_launch(void* const* d_in, const int* in_sizes, int n_in,
                              void* d_out, int out_size, void* d_ws, size_t ws_size,
                              hipStream_t stream) {
    const float* x      = (const float*)d_in[0];
    const float* W1     = (const float*)d_in[1];
    const float* b1     = (const float*)d_in[2];
    const float* tau_m1 = (const float*)d_in[3];
    const float* tau_n  = (const float*)d_in[4];
    const float* W2     = (const float*)d_in[5];
    const float* b2     = (const float*)d_in[6];
    const float* tau_m2 = (const float*)d_in[7];
    const float* mem1_0 = (const float*)d_in[8];
    const float* mem2_0 = (const float*)d_in[9];
    const int*   mask   = (const int*)d_in[10];
    float* out = (float*)d_out;

    float* ws = (float*)d_ws;
    size_t F = 0;
    float* alpha1 = ws + F; F += 1024;
    float* beta   = ws + F; F += 4096;
    float* alpha2 = ws + F; F += 32;
    float* mem1   = ws + F; F += BATCH * NHID;
    float* mem2   = ws + F; F += BATCH * NOUT;
    float* spk2   = ws + F; F += BATCH * NOUT;
    float* d_inp  = ws + F; F += BATCH * NR;
    float* W1xT   = ws + F; F += (size_t)NIN * NR;
    float* W1hTb  = ws + F; F += (size_t)256 * 16384;
    float* W2T    = ws + F; F += NHID * 32;
    uint32_t* spkg = (uint32_t*)(ws + F); F += 2 * BATCH * 64;
    float* ffx = ws + F;

    size_t ws_f = ws_size / 4;
    size_t avail = (ws_f > F) ? (ws_f - F) : 0;
    size_t per_t = (size_t)BATCH * NR;          // 524288 floats per timestep
    int Tc = (int)(avail / per_t);
    if (Tc < 1) Tc = 1;
    if (Tc > TSTEPS) Tc = TSTEPS;

    hipLaunchKernelGGL(setup_small, dim3(128), dim3(256), 0, stream,
                       tau_m1, tau_n, tau_m2, W2, alpha1, beta, alpha2, W2T);
    hipLaunchKernelGGL(setup_weights, dim3(2048), dim3(256), 0, stream, W1, mask, W1xT, W1hTb);
    hipLaunchKernelGGL(init_state, dim3(2048), dim3(256), 0, stream,
                       mem1_0, mem2_0, mem1, mem2, spk2, d_inp, spkg);

    int chunk_start = 0;
    while (chunk_start < TSTEPS) {
        int tc = TSTEPS - chunk_start;
        if (tc > Tc) tc = Tc;
        hipLaunchKernelGGL(ffx_gemm, dim3(tc, 32), dim3(256), 0, stream,
                           x, W1xT, b1, ffx, chunk_start);

        int last = (chunk_start + tc >= TSTEPS) ? 1 : 0;
        int t0v = chunk_start, tcv = tc, lastv = last;
        void* args[] = { &alpha1, &beta, &alpha2, &mem1, &mem2, &spk2, &d_inp,
                         &W1hTb, &W2T, &ffx, &b2, &out, &spkg, &t0v, &tcv, &lastv };
        hipError_t ce = hipLaunchCooperativeKernel(reinterpret_cast<void*>(persist_kernel),
                                                   dim3(256), dim3(1024), args, 0, stream);
        if (ce != hipSuccess) {
            // fallback: per-step kernels (identical math)
            for (int dt = 0; dt < tc; ++dt) {
                int tt = chunk_start + dt;
                const uint32_t* prev = spkg + (size_t)((tt + 1) & 1) * (BATCH * 64);
                uint32_t* next = spkg + (size_t)(tt & 1) * (BATCH * 64);
                hipLaunchKernelGGL(step_kernel, dim3(256), dim3(512), 0, stream,
                                   alpha1, beta, alpha2, mem1, mem2, spk2, d_inp, W1hTb, W2T,
                                   ffx, b2, out, prev, next, tt, dt);
            }
            if (last) {
                const uint32_t* prev = spkg + (size_t)((TSTEPS + 1) & 1) * (BATCH * 64);
                uint32_t* next = spkg + (size_t)(TSTEPS & 1) * (BATCH * 64);
                hipLaunchKernelGGL(step_kernel, dim3(8), dim3(512), 0, stream,
                                   alpha1, beta, alpha2, mem1, mem2, spk2, d_inp, W1hTb, W2T,
                                   ffx, b2, out, prev, next, TSTEPS, 0);
            }
        }
        chunk_start += tc;
    }
}

// Round 3
// 10740.183 us; speedup vs baseline: 4.5166x; 4.5166x over previous
//
#include <hip/hip_runtime.h>
#include <stdint.h>

#define BATCH 128
#define TSTEPS 250
#define NIN 700
#define NHID 1024
#define NBR 4
#define NOUT 20
#define KDIM 1724          // NIN + NHID
#define NR 4096            // NHID * NBR
#define VTH 0.5f

// ---------------- setup kernels ----------------

__global__ void setup_small(const float* __restrict__ tau_m1, const float* __restrict__ tau_n,
                            const float* __restrict__ tau_m2, const float* __restrict__ W2,
                            float* __restrict__ alpha1, float* __restrict__ beta,
                            float* __restrict__ alpha2, float* __restrict__ W2T) {
    int i = blockIdx.x * blockDim.x + threadIdx.x;
    if (i < NHID)  alpha1[i] = 1.f / (1.f + expf(-tau_m1[i]));
    if (i < NR)    beta[i]   = 1.f / (1.f + expf(-tau_n[i]));   // tau_n row-major [HID][BR] == flat r
    if (i < 32)    alpha2[i] = (i < NOUT) ? 1.f / (1.f + expf(-tau_m2[i])) : 0.f;
    if (i < NHID * 32) {                                        // W2T padded [1024][32]
        int j = i >> 5, o = i & 31;
        W2T[i] = (o < NOUT) ? W2[o * NHID + j] : 0.f;
    }
}

// W1xT[k][r] (k<700) and W1hTb[blk][n][16] masked transposes
__global__ void setup_weights(const float* __restrict__ W1, const int* __restrict__ mask,
                              float* __restrict__ W1xT, float* __restrict__ W1hTb) {
    const int total1 = NIN * NR;            // 2,867,200
    const int total2 = 256 * 16384;         // 4,194,304
    for (int i = blockIdx.x * blockDim.x + threadIdx.x; i < total1 + total2;
         i += gridDim.x * blockDim.x) {
        if (i < total1) {
            int k = i >> 12, r = i & 4095;
            size_t src = (size_t)r * KDIM + k;
            W1xT[i] = W1[src] * (float)mask[src];
        } else {
            int j = i - total1;
            int blk = j >> 14, rem = j & 16383;
            int n = rem >> 4, rl = rem & 15;
            int r = (blk << 4) + rl;
            size_t src = (size_t)r * KDIM + NIN + n;
            W1hTb[j] = W1[src] * (float)mask[src];
        }
    }
}

__global__ void init_state(const float* __restrict__ mem1_0, const float* __restrict__ mem2_0,
                           float* __restrict__ mem1, float* __restrict__ mem2,
                           float* __restrict__ spk2, float* __restrict__ d_inp,
                           uint32_t* __restrict__ spkg) {
    int i = blockIdx.x * blockDim.x + threadIdx.x;
    if (i < BATCH * NR) d_inp[i] = 0.f;
    if (i < BATCH * NHID) mem1[i] = mem1_0[i];
    if (i < BATCH * NOUT) { mem2[i] = mem2_0[i]; spk2[i] = 0.f; }
    if (i < 2 * BATCH * 64) spkg[i] = 0u;   // both spike-mask buffers
}

// ---------------- FFX GEMM: ffx[dt][b][r] = sum_k x[b][t0+dt][k]*W1xT[k][r] + b1[r] ----------------

#define GBM 128
#define GBN 128
#define GBK 16

__global__ __launch_bounds__(256) void ffx_gemm(const float* __restrict__ x,
                                                const float* __restrict__ W1xT,
                                                const float* __restrict__ b1,
                                                float* __restrict__ ffx, int t0) {
    __shared__ float As[GBK][GBM];
    __shared__ float Bs[GBK][GBN];
    int dt = blockIdx.x, bn = blockIdx.y;
    int tid = threadIdx.x;
    int tn = tid & 15, tm = tid >> 4;

    float acc[8][8];
#pragma unroll
    for (int i = 0; i < 8; ++i)
#pragma unroll
        for (int j = 0; j < 8; ++j) acc[i][j] = 0.f;

    // A-load mapping: 2 threads per row; row within tile == batch index
    int m_l = tid >> 1;
    const float* xrow = x + ((size_t)m_l * TSTEPS + t0 + dt) * NIN;
    int kh = (tid & 1) * 8;
    // B-load mapping
    int kb = tid >> 4;
    int nb = (tid & 15) * 8;

    for (int k0 = 0; k0 < NIN; k0 += GBK) {
        float av[8];
#pragma unroll
        for (int u = 0; u < 8; ++u) {
            int k = k0 + kh + u;
            av[u] = (k < NIN) ? xrow[k] : 0.f;
        }
#pragma unroll
        for (int u = 0; u < 8; ++u) As[kh + u][m_l] = av[u];

        bool kok = (k0 + kb) < NIN;
        const float* bp = W1xT + (size_t)(k0 + kb) * NR + bn * GBN + nb;
        float bv[8];
#pragma unroll
        for (int u = 0; u < 8; ++u) bv[u] = kok ? bp[u] : 0.f;
#pragma unroll
        for (int u = 0; u < 8; ++u) Bs[kb][nb + u] = bv[u];

        __syncthreads();
#pragma unroll
        for (int kk = 0; kk < GBK; ++kk) {
            float a[8], b[8];
#pragma unroll
            for (int u = 0; u < 8; ++u) a[u] = As[kk][tm * 8 + u];
#pragma unroll
            for (int u = 0; u < 8; ++u) b[u] = Bs[kk][tn * 8 + u];
#pragma unroll
            for (int i = 0; i < 8; ++i)
#pragma unroll
                for (int j = 0; j < 8; ++j) acc[i][j] += a[i] * b[j];
        }
        __syncthreads();
    }

    float bias[8];
#pragma unroll
    for (int j = 0; j < 8; ++j) bias[j] = b1[bn * GBN + tn * 8 + j];
#pragma unroll
    for (int i = 0; i < 8; ++i) {
        int brow = tm * 8 + i;
        float* cp = ffx + ((size_t)dt * BATCH + brow) * NR + bn * GBN + tn * 8;
#pragma unroll
        for (int j = 0; j < 8; ++j) cp[j] = acc[i][j] + bias[j];
    }
}

// ---------------- per-timestep kernel ----------------
// grid 256 blocks x 512 threads. Block blk owns r-tile [blk*16, blk*16+16) = neurons [blk*4, blk*4+4).
// Blocks 0..7 additionally run layer-2 + log_softmax for step t-1 (16 batches each).
// Spike masks: spkg[buf][b][64 words]; byte g of batch b = 4 spike bits of neurons 4g..4g+3.

__global__ __launch_bounds__(512) void step_kernel(
    const float* __restrict__ alpha1, const float* __restrict__ beta,
    const float* __restrict__ alpha2, float* __restrict__ mem1, float* __restrict__ mem2,
    float* __restrict__ spk2, float* __restrict__ d_inp,
    const float* __restrict__ W1hTb, const float* __restrict__ W2T,
    const float* __restrict__ ffx, const float* __restrict__ b2,
    float* __restrict__ out, const uint32_t* __restrict__ spkg_prev,
    uint32_t* __restrict__ spkg_next, int t, int t_local) {
    __shared__ float lds_W[NHID * 17];      // padded: conflict-free column reads
    __shared__ uint32_t lds_mask[BATCH * 64];

    int blk = blockIdx.x;
    int tid = threadIdx.x;
    int r_l = tid & 15;
    int bg = tid >> 4;
    int r_g = (blk << 4) + r_l;
    int neuron = (blk << 2) + (r_l >> 2);

    // ---- prefetch per-thread state (issue loads before staging; consumed after barrier)
    float ffp[4], dip[4], memp[4], beta_r = 0.f, al = 0.f;
    if (t < TSTEPS) {
        beta_r = beta[r_g];
        al = alpha1[neuron];
#pragma unroll
        for (int i = 0; i < 4; ++i) {
            int b = bg * 4 + i;
            ffp[i]  = ffx[((size_t)t_local * BATCH + b) * NR + r_g];
            dip[i]  = d_inp[(size_t)b * NR + r_g];
            memp[i] = mem1[b * NHID + neuron];
        }
    }
    float m2 = 0.f, s2 = 0.f, a2 = 0.f, bo = 0.f;
    int b2b = 0, o2 = 0;
    if (t > 0 && blk < 8) {
        b2b = (blk << 4) + (tid >> 5);
        o2 = tid & 31;
        if (o2 < NOUT) {
            a2 = alpha2[o2];
            bo = b2[o2];
            m2 = mem2[b2b * NOUT + o2];
            s2 = spk2[b2b * NOUT + o2];
        }
    }

    // ---- stage weights + masks
    if (t < TSTEPS) {
        const float4* wsrc = (const float4*)(W1hTb + (size_t)blk * 16384);
        for (int i4 = tid; i4 < 4096; i4 += 512) {
            float4 v = wsrc[i4];
            int n = i4 >> 2, rb = (i4 & 3) * 4;
            lds_W[n * 17 + rb + 0] = v.x;
            lds_W[n * 17 + rb + 1] = v.y;
            lds_W[n * 17 + rb + 2] = v.z;
            lds_W[n * 17 + rb + 3] = v.w;
        }
    }
    for (int i = tid; i < BATCH * 64; i += 512) lds_mask[i] = spkg_prev[i];
    __syncthreads();

    // ---------- phase 1: recurrent accumulate + dendrite + mem1 + spike ----------
    if (t < TSTEPS) {
        int wv = blk >> 2;
        int bitbase = ((blk & 3) << 3) + (r_l >> 2);

#pragma unroll
        for (int i = 0; i < 4; ++i) {
            int b = bg * 4 + i;
            const uint32_t* mw = &lds_mask[b * 64];
            float a = 0.f;
            for (int w = 0; w < 64; ++w) {
                uint32_t bits = mw[w];
                while (bits) {
                    int p = __builtin_ctz(bits);
                    bits &= bits - 1;
                    int n = (w << 4) + ((p >> 3) << 2) + (p & 7);
                    a += lds_W[n * 17 + r_l];
                }
            }
            float ff = a + ffp[i];
            float di = beta_r * dip[i] + (1.f - beta_r) * ff;
            d_inp[(size_t)b * NR + r_g] = di;
            float ls = di + __shfl_xor(di, 1);
            ls += __shfl_xor(ls, 2);
            float sp_prev = (float)((mw[wv] >> bitbase) & 1u);
            float mn = memp[i] * al + (1.f - al) * ls - VTH * sp_prev;
            bool spk = (mn - VTH) > 0.f;
            if ((r_l & 3) == 0) mem1[b * NHID + neuron] = mn;
            unsigned long long bal = __ballot(spk && ((r_l & 3) == 0));
            if (r_l == 0) {
                int base = (bg & 3) << 4;
                uint32_t nib = (uint32_t)((bal >> base) & 1ull) |
                               ((uint32_t)((bal >> (base + 4)) & 1ull) << 1) |
                               ((uint32_t)((bal >> (base + 8)) & 1ull) << 2) |
                               ((uint32_t)((bal >> (base + 12)) & 1ull) << 3);
                ((uint8_t*)spkg_next)[b * 256 + blk] = (uint8_t)nib;
            }
        }
    }

    // ---------- phase 2 (for step t-1): layer 2 + log_softmax ----------
    if (t > 0 && blk < 8) {
        const uint32_t* mw = &lds_mask[b2b * 64];
        float d2 = bo;
        for (int w = 0; w < 64; ++w) {
            uint32_t bits = mw[w];
            while (bits) {
                int p = __builtin_ctz(bits);
                bits &= bits - 1;
                int n = (w << 4) + ((p >> 3) << 2) + (p & 7);
                d2 += W2T[(n << 5) + o2];
            }
        }
        float m2n = m2 * a2 + (1.f - a2) * d2 - VTH * s2;
        if (o2 < NOUT) {
            mem2[b2b * NOUT + o2] = m2n;
            spk2[b2b * NOUT + o2] = ((m2n - VTH) > 0.f) ? 1.f : 0.f;
        }
        float v = (o2 < NOUT) ? m2n : -3.4e38f;
#pragma unroll
        for (int off = 16; off >= 1; off >>= 1) v = fmaxf(v, __shfl_xor(v, off, 32));
        float e = (o2 < NOUT) ? expf(m2n - v) : 0.f;
        float s = e;
#pragma unroll
        for (int off = 16; off >= 1; off >>= 1) s += __shfl_xor(s, off, 32);
        if (o2 < NOUT) out[((size_t)b2b * NOUT + o2) * TSTEPS + (t - 1)] = (m2n - v) - logf(s);
    }
}

// ---------------- host ----------------

extern "C" void kernel_launch(void* const* d_in, const int* in_sizes, int n_in,
                              void* d_out, int out_size, void* d_ws, size_t ws_size,
                              hipStream_t stream) {
    const float* x      = (const float*)d_in[0];
    const float* W1     = (const float*)d_in[1];
    const float* b1     = (const float*)d_in[2];
    const float* tau_m1 = (const float*)d_in[3];
    const float* tau_n  = (const float*)d_in[4];
    const float* W2     = (const float*)d_in[5];
    const float* b2     = (const float*)d_in[6];
    const float* tau_m2 = (const float*)d_in[7];
    const float* mem1_0 = (const float*)d_in[8];
    const float* mem2_0 = (const float*)d_in[9];
    const int*   mask   = (const int*)d_in[10];
    float* out = (float*)d_out;

    float* ws = (float*)d_ws;
    size_t F = 0;
    float* alpha1 = ws + F; F += 1024;
    float* beta   = ws + F; F += 4096;
    float* alpha2 = ws + F; F += 32;
    float* mem1   = ws + F; F += BATCH * NHID;
    float* mem2   = ws + F; F += BATCH * NOUT;
    float* spk2   = ws + F; F += BATCH * NOUT;
    float* d_inp  = ws + F; F += BATCH * NR;
    float* W1xT   = ws + F; F += (size_t)NIN * NR;
    float* W1hTb  = ws + F; F += (size_t)256 * 16384;
    float* W2T    = ws + F; F += NHID * 32;
    uint32_t* spkg = (uint32_t*)(ws + F); F += 2 * BATCH * 64;
    float* ffx = ws + F;

    size_t ws_f = ws_size / 4;
    size_t avail = (ws_f > F) ? (ws_f - F) : 0;
    size_t per_t = (size_t)BATCH * NR;          // 524288 floats per timestep
    int Tc = (int)(avail / per_t);
    if (Tc < 1) Tc = 1;
    if (Tc > TSTEPS) Tc = TSTEPS;

    hipLaunchKernelGGL(setup_small, dim3(128), dim3(256), 0, stream,
                       tau_m1, tau_n, tau_m2, W2, alpha1, beta, alpha2, W2T);
    hipLaunchKernelGGL(setup_weights, dim3(2048), dim3(256), 0, stream, W1, mask, W1xT, W1hTb);
    hipLaunchKernelGGL(init_state, dim3(2048), dim3(256), 0, stream,
                       mem1_0, mem2_0, mem1, mem2, spk2, d_inp, spkg);

    int chunk_start = 0;
    while (chunk_start < TSTEPS) {
        int tc = TSTEPS - chunk_start;
        if (tc > Tc) tc = Tc;
        hipLaunchKernelGGL(ffx_gemm, dim3(tc, 32), dim3(256), 0, stream,
                           x, W1xT, b1, ffx, chunk_start);
        for (int dt = 0; dt < tc; ++dt) {
            int tt = chunk_start + dt;
            const uint32_t* prev = spkg + (size_t)((tt + 1) & 1) * (BATCH * 64);
            uint32_t* next = spkg + (size_t)(tt & 1) * (BATCH * 64);
            hipLaunchKernelGGL(step_kernel, dim3(256), dim3(512), 0, stream,
                               alpha1, beta, alpha2, mem1, mem2, spk2, d_inp, W1hTb, W2T,
                               ffx, b2, out, prev, next, tt, dt);
        }
        chunk_start += tc;
    }
    // final phase-2 (t = 249 outputs)
    {
        const uint32_t* prev = spkg + (size_t)((TSTEPS + 1) & 1) * (BATCH * 64);
        uint32_t* next = spkg + (size_t)(TSTEPS & 1) * (BATCH * 64);
        hipLaunchKernelGGL(step_kernel, dim3(8), dim3(512), 0, stream,
                           alpha1, beta, alpha2, mem1, mem2, spk2, d_inp, W1hTb, W2T,
                           ffx, b2, out, prev, next, TSTEPS, 0);
    }
}

// Round 5
// 7088.537 us; speedup vs baseline: 6.8433x; 1.5151x over previous
//
#include <hip/hip_runtime.h>
#include <stdint.h>

#define BATCH 128
#define TSTEPS 250
#define NIN 700
#define NHID 1024
#define NBR 4
#define NOUT 20
#define KDIM 1724          // NIN + NHID
#define NR 4096            // NHID * NBR
#define VTH 0.5f

// ---------------- setup kernels ----------------

__global__ void setup_small(const float* __restrict__ tau_m1, const float* __restrict__ tau_n,
                            const float* __restrict__ tau_m2, const float* __restrict__ W2,
                            float* __restrict__ alpha1, float* __restrict__ beta,
                            float* __restrict__ alpha2, float* __restrict__ W2T) {
    int i = blockIdx.x * blockDim.x + threadIdx.x;
    if (i < NHID)  alpha1[i] = 1.f / (1.f + expf(-tau_m1[i]));
    if (i < NR)    beta[i]   = 1.f / (1.f + expf(-tau_n[i]));   // tau_n row-major [HID][BR] == flat r
    if (i < 32)    alpha2[i] = (i < NOUT) ? 1.f / (1.f + expf(-tau_m2[i])) : 0.f;
    if (i < NHID * 32) {                                        // W2T padded [1024][32]
        int j = i >> 5, o = i & 31;
        W2T[i] = (o < NOUT) ? W2[o * NHID + j] : 0.f;
    }
}

// W1xT[k][r] (k<700) and W1hTb[blk][n][16] masked transposes
__global__ void setup_weights(const float* __restrict__ W1, const int* __restrict__ mask,
                              float* __restrict__ W1xT, float* __restrict__ W1hTb) {
    const int total1 = NIN * NR;            // 2,867,200
    const int total2 = 256 * 16384;         // 4,194,304
    for (int i = blockIdx.x * blockDim.x + threadIdx.x; i < total1 + total2;
         i += gridDim.x * blockDim.x) {
        if (i < total1) {
            int k = i >> 12, r = i & 4095;
            size_t src = (size_t)r * KDIM + k;
            W1xT[i] = W1[src] * (float)mask[src];
        } else {
            int j = i - total1;
            int blk = j >> 14, rem = j & 16383;
            int n = rem >> 4, rl = rem & 15;
            int r = (blk << 4) + rl;
            size_t src = (size_t)r * KDIM + NIN + n;
            W1hTb[j] = W1[src] * (float)mask[src];
        }
    }
}

__global__ void init_state(const float* __restrict__ mem1_0, const float* __restrict__ mem2_0,
                           float* __restrict__ mem1, float* __restrict__ mem2,
                           float* __restrict__ spk2, float* __restrict__ d_inp,
                           uint32_t* __restrict__ spkg, uint32_t* __restrict__ cnt) {
    int i = blockIdx.x * blockDim.x + threadIdx.x;
    if (i < BATCH * NR) d_inp[i] = 0.f;
    if (i < BATCH * NHID) mem1[i] = mem1_0[i];
    if (i < BATCH * NOUT) { mem2[i] = mem2_0[i]; spk2[i] = 0.f; }
    if (i < 8192) spkg[i] = 0u;   // both spike-word buffers (2 x 256 x 16 dwords)
    if (i == 0) cnt[0] = 0u;      // barrier counter — re-zeroed every launch/replay
}

// ---------------- FFX GEMM: ffx[dt][b][r] = sum_k x[b][t0+dt][k]*W1xT[k][r] + b1[r] ----------------

#define GBM 128
#define GBN 128
#define GBK 16

__global__ __launch_bounds__(256) void ffx_gemm(const float* __restrict__ x,
                                                const float* __restrict__ W1xT,
                                                const float* __restrict__ b1,
                                                float* __restrict__ ffx, int t0) {
    __shared__ float As[GBK][GBM];
    __shared__ float Bs[GBK][GBN];
    int dt = blockIdx.x, bn = blockIdx.y;
    int tid = threadIdx.x;
    int tn = tid & 15, tm = tid >> 4;

    float acc[8][8];
#pragma unroll
    for (int i = 0; i < 8; ++i)
#pragma unroll
        for (int j = 0; j < 8; ++j) acc[i][j] = 0.f;

    int m_l = tid >> 1;
    const float* xrow = x + ((size_t)m_l * TSTEPS + t0 + dt) * NIN;
    int kh = (tid & 1) * 8;
    int kb = tid >> 4;
    int nb = (tid & 15) * 8;

    for (int k0 = 0; k0 < NIN; k0 += GBK) {
        float av[8];
#pragma unroll
        for (int u = 0; u < 8; ++u) {
            int k = k0 + kh + u;
            av[u] = (k < NIN) ? xrow[k] : 0.f;
        }
#pragma unroll
        for (int u = 0; u < 8; ++u) As[kh + u][m_l] = av[u];

        bool kok = (k0 + kb) < NIN;
        const float* bp = W1xT + (size_t)(k0 + kb) * NR + bn * GBN + nb;
        float bv[8];
#pragma unroll
        for (int u = 0; u < 8; ++u) bv[u] = kok ? bp[u] : 0.f;
#pragma unroll
        for (int u = 0; u < 8; ++u) Bs[kb][nb + u] = bv[u];

        __syncthreads();
#pragma unroll
        for (int kk = 0; kk < GBK; ++kk) {
            float a[8], b[8];
#pragma unroll
            for (int u = 0; u < 8; ++u) a[u] = As[kk][tm * 8 + u];
#pragma unroll
            for (int u = 0; u < 8; ++u) b[u] = Bs[kk][tn * 8 + u];
#pragma unroll
            for (int i = 0; i < 8; ++i)
#pragma unroll
                for (int j = 0; j < 8; ++j) acc[i][j] += a[i] * b[j];
        }
        __syncthreads();
    }

    float bias[8];
#pragma unroll
    for (int j = 0; j < 8; ++j) bias[j] = b1[bn * GBN + tn * 8 + j];
#pragma unroll
    for (int i = 0; i < 8; ++i) {
        int brow = tm * 8 + i;
        float* cp = ffx + ((size_t)dt * BATCH + brow) * NR + bn * GBN + tn * 8;
#pragma unroll
        for (int j = 0; j < 8; ++j) cp[j] = acc[i][j] + bias[j];
    }
}

// ---------------- persistent time-loop kernel (custom agent-scope barrier) ----------------
// 256 blocks x 1024 threads; ~103 KB LDS forces 1 block/CU -> all 256 co-resident.
// Block blk owns r-tile [blk*16, blk*16+16) = neurons [blk*4, blk*4+4).
// Thread (bg=tid>>4, r_l=tid&15) owns batches {2bg, 2bg+1}.
// Spike words: spkg[parity][blk][g], g=0..15; nibble j of dword g = 4 spike bits
// (neurons 4blk..4blk+3) of batch 8g+j.
// Per-batch masks: 32 dwords, bit p of word w = spike of neuron 32w+p.

__global__ __launch_bounds__(1024) void persist2(
    const float* __restrict__ alpha1, const float* __restrict__ beta,
    const float* __restrict__ alpha2, float* __restrict__ mem1,
    float* __restrict__ mem2, float* __restrict__ spk2,
    float* __restrict__ d_inp, const float* __restrict__ W1hTb,
    const float* __restrict__ W2T, const float* __restrict__ ffx,
    const float* __restrict__ b2v, float* __restrict__ out,
    uint32_t* __restrict__ spkg, uint32_t* __restrict__ cnt,
    int t0, int tc, int last, int epoch0) {
    __shared__ float lds_W[NHID * 17];       // 69,632 B (padded, conflict-free column reads)
    __shared__ uint32_t lds_spk[4096];       // 16,384 B (raw spike words, XOR-swizzled)
    __shared__ uint32_t lds_mask[128 * 33];  // 16,896 B (per-batch 32-word masks, padded)

    const int blk = blockIdx.x;
    const int tid = threadIdx.x;

    // ---- stage recurrent weight slice ONCE for the whole chunk
    {
        const float4* wsrc = (const float4*)(W1hTb + (size_t)blk * 16384);
        for (int i4 = tid; i4 < 4096; i4 += 1024) {
            float4 v = wsrc[i4];
            int n = i4 >> 2, rb = (i4 & 3) * 4;
            lds_W[n * 17 + rb + 0] = v.x;
            lds_W[n * 17 + rb + 1] = v.y;
            lds_W[n * 17 + rb + 2] = v.z;
            lds_W[n * 17 + rb + 3] = v.w;
        }
    }

    const int r_l = tid & 15;
    const int bg  = tid >> 4;                // 0..63
    const int r_g = (blk << 4) + r_l;
    const int neuron = (blk << 2) + (r_l >> 2);
    const float beta_r = beta[r_g];
    const float al = alpha1[neuron];
    const int b0 = bg * 2, b1 = bg * 2 + 1;

    // register-resident layer-1 state
    float di0 = d_inp[(size_t)b0 * NR + r_g];
    float di1 = d_inp[(size_t)b1 * NR + r_g];
    float mm0 = mem1[b0 * NHID + neuron];
    float mm1 = mem1[b1 * NHID + neuron];

    // layer-2 ownership: blocks 0..15, 8 batches each; active threads: (sub&3)==0
    const int o2 = tid & 31;
    const int sub = tid >> 5;                // 0..31
    const bool l2blk = (blk < 16) && ((sub & 3) == 0);
    const int b2b = (blk << 3) + (sub >> 2);
    float m2 = 0.f, s2v = 0.f, a2 = 0.f, bo = 0.f;
    if (l2blk && o2 < NOUT) {
        a2 = alpha2[o2];
        bo = b2v[o2];
        m2 = mem2[b2b * NOUT + o2];
        s2v = spk2[b2b * NOUT + o2];
    }

    const int iters = tc + (last ? 1 : 0);
    for (int it = 0; it < iters; ++it) {
        const int tt = t0 + it;

        // ---- prefetch ffx for this step (private, plain loads)
        float ff0 = 0.f, ff1 = 0.f;
        if (tt < TSTEPS) {
            const float* fr = ffx + (size_t)it * ((size_t)BATCH * NR);
            ff0 = fr[(size_t)b0 * NR + r_g];
            ff1 = fr[(size_t)b1 * NR + r_g];
        }

        // ---- stage spike words (agent-coherent loads; XOR bank-swizzled store)
        {
            const uint32_t* spg = spkg + (size_t)((tt + 1) & 1) * 4096;
#pragma unroll
            for (int k = 0; k < 4; ++k) {
                int idx = tid + (k << 10);
                lds_spk[idx ^ ((idx >> 7) & 31)] =
                    __hip_atomic_load(&spg[idx], __ATOMIC_RELAXED, __HIP_MEMORY_SCOPE_AGENT);
            }
        }
        __syncthreads();

        // ---- transpose to per-batch 32-word dense masks: bit p of word w = neuron 32w+p
        {
            const int w = tid & 31;          // mask word
            const int bq = tid >> 5;         // batch quad 0..31
            const int g = bq >> 1;           // source dword index (batch octet)
            uint32_t sw[8];
#pragma unroll
            for (int m = 0; m < 8; ++m) {
                int raw = (w << 7) + (m << 4) + g;   // block (8w+m), word16 g
                sw[m] = lds_spk[raw ^ (w & 31)];
            }
#pragma unroll
            for (int u = 0; u < 4; ++u) {
                const int b = (bq << 2) + u;
                const int j = ((bq & 1) << 2) + u;   // b & 7
                uint32_t word = 0;
#pragma unroll
                for (int m = 0; m < 8; ++m)
                    word |= ((sw[m] >> (j << 2)) & 0xFu) << (m << 2);
                lds_mask[b * 33 + w] = word;
            }
        }
        __syncthreads();

        uint32_t* spn = spkg + (size_t)(tt & 1) * 4096;

        // ---------- phase 1: recurrent accumulate + dendrite + mem1 + spike ----------
        if (tt < TSTEPS) {
            const uint32_t* mw0 = &lds_mask[b0 * 33];
            const uint32_t* mw1 = &lds_mask[b1 * 33];
            float acc0 = 0.f, acc1 = 0.f;
            for (int w = 0; w < 32; ++w) {
                uint32_t bits0 = mw0[w];
                while (bits0) {
                    int p = __builtin_ctz(bits0);
                    bits0 &= bits0 - 1;
                    acc0 += lds_W[((w << 5) + p) * 17 + r_l];
                }
                uint32_t bits1 = mw1[w];
                while (bits1) {
                    int p = __builtin_ctz(bits1);
                    bits1 &= bits1 - 1;
                    acc1 += lds_W[((w << 5) + p) * 17 + r_l];
                }
            }
            di0 = beta_r * di0 + (1.f - beta_r) * (acc0 + ff0);
            di1 = beta_r * di1 + (1.f - beta_r) * (acc1 + ff1);
            float ls0 = di0 + __shfl_xor(di0, 1); ls0 += __shfl_xor(ls0, 2);
            float ls1 = di1 + __shfl_xor(di1, 1); ls1 += __shfl_xor(ls1, 2);
            float sp0 = (float)((mw0[neuron >> 5] >> (neuron & 31)) & 1u);
            float sp1 = (float)((mw1[neuron >> 5] >> (neuron & 31)) & 1u);
            float mn0 = mm0 * al + (1.f - al) * ls0 - VTH * sp0;  mm0 = mn0;
            float mn1 = mm1 * al + (1.f - al) * ls1 - VTH * sp1;  mm1 = mn1;
            bool sk0 = (mn0 - VTH) > 0.f;
            bool sk1 = (mn1 - VTH) > 0.f;
            unsigned long long bal0 = __ballot(sk0 && ((r_l & 3) == 0));
            unsigned long long bal1 = __ballot(sk1 && ((r_l & 3) == 0));
            uint32_t dw = 0;
#pragma unroll
            for (int q = 0; q < 4; ++q) {
                uint32_t nb0 = (uint32_t)((bal0 >> (q * 16)) & 1ull)
                             | ((uint32_t)((bal0 >> (q * 16 + 4)) & 1ull) << 1)
                             | ((uint32_t)((bal0 >> (q * 16 + 8)) & 1ull) << 2)
                             | ((uint32_t)((bal0 >> (q * 16 + 12)) & 1ull) << 3);
                uint32_t nb1 = (uint32_t)((bal1 >> (q * 16)) & 1ull)
                             | ((uint32_t)((bal1 >> (q * 16 + 4)) & 1ull) << 1)
                             | ((uint32_t)((bal1 >> (q * 16 + 8)) & 1ull) << 2)
                             | ((uint32_t)((bal1 >> (q * 16 + 12)) & 1ull) << 3);
                dw |= (nb0 << (q * 8)) | (nb1 << (q * 8 + 4));
            }
            if ((tid & 63) == 0)
                __hip_atomic_store(&spn[(blk << 4) + (tid >> 6)], dw, __ATOMIC_RELAXED,
                                   __HIP_MEMORY_SCOPE_AGENT);
        }

        // ---------- phase 2 (for step tt-1): layer 2 + log_softmax ----------
        if (tt > 0 && l2blk) {
            const uint32_t* mw = &lds_mask[b2b * 33];
            float d2 = bo;
            for (int w = 0; w < 32; ++w) {
                uint32_t bits = mw[w];
                while (bits) {
                    int p = __builtin_ctz(bits);
                    bits &= bits - 1;
                    d2 += W2T[(((w << 5) + p) << 5) + o2];
                }
            }
            float m2n = m2 * a2 + (1.f - a2) * d2 - VTH * s2v;
            m2 = m2n;
            s2v = ((m2n - VTH) > 0.f) ? 1.f : 0.f;
            float v = (o2 < NOUT) ? m2n : -3.4e38f;
#pragma unroll
            for (int off = 16; off >= 1; off >>= 1) v = fmaxf(v, __shfl_xor(v, off, 32));
            float e = (o2 < NOUT) ? expf(m2n - v) : 0.f;
            float s = e;
#pragma unroll
            for (int off = 16; off >= 1; off >>= 1) s += __shfl_xor(s, off, 32);
            if (o2 < NOUT) out[((size_t)b2b * NOUT + o2) * TSTEPS + (tt - 1)] = (m2n - v) - logf(s);
        }

        // ---------- lightweight grid barrier (one atomic per block, no threadfence) ----------
        if (it + 1 < iters) {
            __syncthreads();   // all threads' spike stores issued before arrive
            if (tid == 0) {
                __hip_atomic_fetch_add(cnt, 1u, __ATOMIC_RELEASE, __HIP_MEMORY_SCOPE_AGENT);
                uint32_t tgt = 256u * (uint32_t)(epoch0 + it + 1);
                while (__hip_atomic_load(cnt, __ATOMIC_RELAXED, __HIP_MEMORY_SCOPE_AGENT) < tgt)
                    __builtin_amdgcn_s_sleep(2);
            }
            __syncthreads();
        }
    }

    // ---- save state for next chunk
    d_inp[(size_t)b0 * NR + r_g] = di0;
    d_inp[(size_t)b1 * NR + r_g] = di1;
    if ((r_l & 3) == 0) {
        mem1[b0 * NHID + neuron] = mm0;
        mem1[b1 * NHID + neuron] = mm1;
    }
    if (l2blk && o2 < NOUT) {
        mem2[b2b * NOUT + o2] = m2;
        spk2[b2b * NOUT + o2] = s2v;
    }
}

// ---------------- host ----------------

extern "C" void kernel_launch(void* const* d_in, const int* in_sizes, int n_in,
                              void* d_out, int out_size, void* d_ws, size_t ws_size,
                              hipStream_t stream) {
    const float* x      = (const float*)d_in[0];
    const float* W1     = (const float*)d_in[1];
    const float* b1     = (const float*)d_in[2];
    const float* tau_m1 = (const float*)d_in[3];
    const float* tau_n  = (const float*)d_in[4];
    const float* W2     = (const float*)d_in[5];
    const float* b2     = (const float*)d_in[6];
    const float* tau_m2 = (const float*)d_in[7];
    const float* mem1_0 = (const float*)d_in[8];
    const float* mem2_0 = (const float*)d_in[9];
    const int*   mask   = (const int*)d_in[10];
    float* out = (float*)d_out;

    float* ws = (float*)d_ws;
    size_t F = 0;
    float* alpha1 = ws + F; F += 1024;
    float* beta   = ws + F; F += 4096;
    float* alpha2 = ws + F; F += 32;
    float* mem1   = ws + F; F += BATCH * NHID;
    float* mem2   = ws + F; F += BATCH * NOUT;
    float* spk2   = ws + F; F += BATCH * NOUT;
    float* d_inp  = ws + F; F += BATCH * NR;
    float* W1xT   = ws + F; F += (size_t)NIN * NR;
    float* W1hTb  = ws + F; F += (size_t)256 * 16384;
    float* W2T    = ws + F; F += NHID * 32;
    uint32_t* spkg = (uint32_t*)(ws + F); F += 2 * BATCH * 64;   // 16384 dwords reserved
    uint32_t* cnt  = (uint32_t*)(ws + F); F += 64;
    float* ffx = ws + F;

    size_t ws_f = ws_size / 4;
    size_t avail = (ws_f > F) ? (ws_f - F) : 0;
    size_t per_t = (size_t)BATCH * NR;          // 524288 floats per timestep
    int Tc = (int)(avail / per_t);
    if (Tc < 1) Tc = 1;
    if (Tc > TSTEPS) Tc = TSTEPS;

    hipLaunchKernelGGL(setup_small, dim3(128), dim3(256), 0, stream,
                       tau_m1, tau_n, tau_m2, W2, alpha1, beta, alpha2, W2T);
    hipLaunchKernelGGL(setup_weights, dim3(2048), dim3(256), 0, stream, W1, mask, W1xT, W1hTb);
    hipLaunchKernelGGL(init_state, dim3(2048), dim3(256), 0, stream,
                       mem1_0, mem2_0, mem1, mem2, spk2, d_inp, spkg, cnt);

    int chunk_start = 0;
    int barriers_done = 0;
    while (chunk_start < TSTEPS) {
        int tc = TSTEPS - chunk_start;
        if (tc > Tc) tc = Tc;
        int last = (chunk_start + tc >= TSTEPS) ? 1 : 0;

        hipLaunchKernelGGL(ffx_gemm, dim3(tc, 32), dim3(256), 0, stream,
                           x, W1xT, b1, ffx, chunk_start);
        hipLaunchKernelGGL(persist2, dim3(256), dim3(1024), 0, stream,
                           alpha1, beta, alpha2, mem1, mem2, spk2, d_inp, W1hTb, W2T,
                           ffx, b2, out, spkg, cnt, chunk_start, tc, last, barriers_done);

        int iters = tc + (last ? 1 : 0);
        barriers_done += iters - 1;
        chunk_start += tc;
    }
}